// Round 3
// baseline (26.430 us; speedup 1.0000x reference)
//
#include <hip/hip_runtime.h>

// Polyphase resampler, up=2 / down=3, FILT=128 taps, fp32.
//   out[2g]   = 2 * sum_{m=0..63} x[31+3g-m] * f[2m+1]
//   out[2g+1] = 2 * sum_{m=0..63} x[33+3g-m] * f[2m]
// x zero-extended outside [0,N). out_len = ceil(2N/3).
//
// R3: persistent blocks + double-buffered LDS tiles + global_load_lds
// staging overlapped with compute; R=4 (48B lane stride -> conflict-free
// b128 window reads); filter via uniform s_load (no LDS filter reads).

constexpr int R    = 4;                // output pairs per thread
constexpr int BT   = 256;              // threads per block
constexpr int PPB  = R * BT;           // 1024 pairs per tile
constexpr int XF   = 3 * PPB + 64;     // 3136 staged floats per tile
constexpr int WIN  = 3 * R + 64;       // 76-float register window (75 used)
constexpr int GRID = 1024;             // persistent blocks (4 per CU)

__device__ __forceinline__ void gload_lds16(const float* g, float* l) {
    __builtin_amdgcn_global_load_lds(
        (const __attribute__((address_space(1))) void*)g,
        (__attribute__((address_space(3))) void*)l, 16, 0, 0);
}

__global__ __launch_bounds__(BT) void resample23_kernel(
    const float* __restrict__ x,
    const float* __restrict__ filt,
    float* __restrict__ out,
    int N, int out_size, int n_tiles)
{
    __shared__ __align__(16) float xs[2][XF];   // 25088 B double buffer

    const int t = threadIdx.x;
    const int w = t >> 6;          // wave id
    const int l = t & 63;          // lane id

    // ---- stage one tile into dst (issues loads; completion at next barrier)
    auto stage = [&](int tile, float* dst) {
        const int tf = 3 * tile * PPB - 32;    // global float idx of dst[0]
        if (tf >= 0 && tf + XF <= N) {
            // interior: 3 x 1KB global_load_lds per wave (linear dest)
            #pragma unroll
            for (int k = 0; k < 3; ++k) {
                const int fo = 768 * w + 256 * k + 4 * l;   // float offset
                gload_lds16(x + tf + fo, dst + fo);
            }
            // tail 64 floats (256 B) via 16 threads
            if (t < 16) {
                float4 v = *reinterpret_cast<const float4*>(x + tf + 3072 + 4 * t);
                *reinterpret_cast<float4*>(dst + 3072 + 4 * t) = v;
            }
        } else {
            // boundary tile (first/last only): guarded scalar fill
            #pragma unroll
            for (int k = 0; k < 4; ++k) {
                int idx = t + BT * k;                 // float4 index
                if (idx < XF / 4) {
                    int f0 = tf + 4 * idx;
                    float4 v;
                    v.x = (f0 + 0 >= 0 && f0 + 0 < N) ? x[f0 + 0] : 0.0f;
                    v.y = (f0 + 1 >= 0 && f0 + 1 < N) ? x[f0 + 1] : 0.0f;
                    v.z = (f0 + 2 >= 0 && f0 + 2 < N) ? x[f0 + 2] : 0.0f;
                    v.w = (f0 + 3 >= 0 && f0 + 3 < N) ? x[f0 + 3] : 0.0f;
                    *reinterpret_cast<float4*>(dst + 4 * idx) = v;
                }
            }
        }
    };

    int tile = blockIdx.x;
    if (tile < n_tiles) stage(tile, xs[0]);
    __syncthreads();

    int cur = 0;
    for (; tile < n_tiles; tile += GRID) {
        // issue next tile's staging before computing current (overlap)
        if (tile + GRID < n_tiles) stage(tile + GRID, xs[cur ^ 1]);

        // ---- per-thread 76-float window from LDS (48B lane stride: conflict-free)
        float xr[WIN];
        const float* wp = xs[cur] + 12 * t;
        #pragma unroll
        for (int i = 0; i < WIN / 4; ++i) {
            float4 v = *reinterpret_cast<const float4*>(wp + 4 * i);
            xr[4*i+0] = v.x; xr[4*i+1] = v.y; xr[4*i+2] = v.z; xr[4*i+3] = v.w;
        }

        // ---- polyphase FIR; filter coeffs via wave-uniform loads (s_load)
        float acc[2 * R];
        #pragma unroll
        for (int i = 0; i < 2 * R; ++i) acc[i] = 0.0f;

        #pragma unroll
        for (int mm = 0; mm < 32; ++mm) {
            float4 c = *reinterpret_cast<const float4*>(filt + 4 * mm);
            // c.x=f[4mm] c.y=f[4mm+1] c.z=f[4mm+2] c.w=f[4mm+3]
            const int m0 = 2 * mm, m1 = 2 * mm + 1;
            #pragma unroll
            for (int p = 0; p < R; ++p) {
                acc[2*p]     += xr[63 - m0 + 3*p] * c.y;   // even, f[2m0+1]
                acc[2*p + 1] += xr[65 - m0 + 3*p] * c.x;   // odd,  f[2m0]
                acc[2*p]     += xr[63 - m1 + 3*p] * c.w;   // even, f[2m1+1]
                acc[2*p + 1] += xr[65 - m1 + 3*p] * c.z;   // odd,  f[2m1]
            }
        }

        // ---- store 8 contiguous outputs (x2 scale folded here)
        const int j0 = 2 * (tile * PPB + R * t);
        if (j0 + 2 * R <= out_size) {
            float4* ov = reinterpret_cast<float4*>(out + j0);
            #pragma unroll
            for (int q = 0; q < (2 * R) / 4; ++q)
                ov[q] = make_float4(2.0f * acc[4*q+0], 2.0f * acc[4*q+1],
                                    2.0f * acc[4*q+2], 2.0f * acc[4*q+3]);
        } else {
            #pragma unroll
            for (int i = 0; i < 2 * R; ++i)
                if (j0 + i < out_size) out[j0 + i] = 2.0f * acc[i];
        }

        __syncthreads();   // drains next-tile gload_lds + protects buffer swap
        cur ^= 1;
    }
}

extern "C" void kernel_launch(void* const* d_in, const int* in_sizes, int n_in,
                              void* d_out, int out_size, void* d_ws, size_t ws_size,
                              hipStream_t stream)
{
    const float* x    = (const float*)d_in[0];
    const float* filt = (const float*)d_in[1];
    float* out        = (float*)d_out;
    const int N       = in_sizes[0];

    const int n_pairs = (out_size + 1) / 2;
    const int n_tiles = (n_pairs + PPB - 1) / PPB;
    resample23_kernel<<<GRID, BT, 0, stream>>>(x, filt, out, N, out_size, n_tiles);
}

// Round 4
// 17.855 us; speedup vs baseline: 1.4802x; 1.4802x over previous
//
#include <hip/hip_runtime.h>
#include <hip/hip_bf16.h>

// Polyphase resampler, up=2/down=3, 128-tap FIR, via bf16 MFMA.
//   out[2g]   = 2 * sum_m x[31+3g-m] * f[2m+1]
//   out[2g+1] = 2 * sum_m x[33+3g-m] * f[2m]
// Reformulated with window W_g[k] = x[3g-32+k] and reversed filters
//   fe_r[u]=f[127-2u], fo_r[u]=f[126-2u]:
//   out[2g]   = 2 * sum_{u=0..63} W_g[u]   * fe_r[u]
//   out[2g+1] = 2 * sum_{u=0..63} W_g[u+2] * fo_r[u]
// MFMA 16x16x32 bf16, K=96 (3 chunks): A[i][k] = x[3(g0+8i)-32+k] (im2col
// from LDS), B[k][j] with j=(delta<<1)|ph embeds 8 output shifts x 2 phases:
//   B[k][2d+ph] = (ph? fo_r : fe_r)[k-3d-2ph]  (0 outside [0,63])
// => D[i][j] = out[2*g0 + 16*i + j] : 256 contiguous outputs per triple.

typedef __bf16 bf16x8 __attribute__((ext_vector_type(8)));
typedef float  f32x4  __attribute__((ext_vector_type(4)));

constexpr int BT  = 256;            // 4 waves
constexpr int GPB = 4096;           // output pairs (g) per block
constexpr int XT  = 3 * GPB + 96;   // 12384 staged bf16 x-elements
constexpr int XT4 = XT / 4;         // 3096 float4 groups

__global__ __launch_bounds__(BT) void resample23_mfma(
    const float* __restrict__ x,
    const float* __restrict__ filt,
    float* __restrict__ out,
    int N, int out_size)
{
    __shared__ __align__(16) unsigned short xs[XT];   // bf16 x tile

    const int t = threadIdx.x;
    const int w = t >> 6;
    const int l = t & 63;
    const int G0 = blockIdx.x * GPB;
    const long F0 = 3L * G0 - 32;     // global float idx of xs[0]

    // ---- stage x tile: f32 global -> bf16 LDS (coalesced float4) ----
    const bool interior = (F0 >= 0) && (F0 + XT <= (long)N);
    #pragma unroll
    for (int r = 0; r < (XT4 + BT - 1) / BT; ++r) {
        int idx = t + BT * r;
        if (idx < XT4) {
            long f0 = F0 + 4L * idx;
            float4 v;
            if (interior) {
                v = *reinterpret_cast<const float4*>(x + f0);
            } else {
                v.x = (f0 + 0 >= 0 && f0 + 0 < N) ? x[f0 + 0] : 0.0f;
                v.y = (f0 + 1 >= 0 && f0 + 1 < N) ? x[f0 + 1] : 0.0f;
                v.z = (f0 + 2 >= 0 && f0 + 2 < N) ? x[f0 + 2] : 0.0f;
                v.w = (f0 + 3 >= 0 && f0 + 3 < N) ? x[f0 + 3] : 0.0f;
            }
            __hip_bfloat162 p0 = __float22bfloat162_rn(make_float2(v.x, v.y));
            __hip_bfloat162 p1 = __float22bfloat162_rn(make_float2(v.z, v.w));
            *reinterpret_cast<__hip_bfloat162*>(&xs[4 * idx + 0]) = p0;
            *reinterpret_cast<__hip_bfloat162*>(&xs[4 * idx + 2]) = p1;
        }
    }

    // ---- build B fragments (once): lane l -> col j=l&15, k=8*(l>>4)+e ----
    const int j   = l & 15;
    const int kq  = (l >> 4) * 8;
    const int dlt = j >> 1;
    const int ph  = j & 1;
    bf16x8 Bf[3];
    #pragma unroll
    for (int kc = 0; kc < 3; ++kc) {
        #pragma unroll
        for (int e = 0; e < 8; ++e) {
            int k = 32 * kc + kq + e;
            int v = k - 3 * dlt - 2 * ph;           // tap index u
            float fv = (v >= 0 && v < 64) ? filt[(ph ? 126 : 127) - 2 * v] : 0.0f;
            Bf[kc][e] = (__bf16)fv;
        }
    }

    __syncthreads();

    // ---- 8 MFMA-triples per wave: 256 contiguous outputs each ----
    const char* xsb = reinterpret_cast<const char*>(xs);
    #pragma unroll
    for (int s = 0; s < 8; ++s) {
        const int g0   = G0 + 128 * (8 * w + s);        // local c00 = 384*(8w+s)
        const int boff = 768 * (8 * w + s) + 48 * (l & 15) + 16 * (l >> 4);

        f32x4 acc = {0.0f, 0.0f, 0.0f, 0.0f};
        #pragma unroll
        for (int kc = 0; kc < 3; ++kc) {
            bf16x8 a = *reinterpret_cast<const bf16x8*>(xsb + boff + 64 * kc);
            acc = __builtin_amdgcn_mfma_f32_16x16x32_bf16(a, Bf[kc], acc, 0, 0, 0);
        }

        // D[i][j]: col=l&15, row=4*(l>>4)+r  ->  out[2*g0 + 16*row + col]
        const int obase = 2 * g0 + 16 * (4 * (l >> 4)) + j;
        #pragma unroll
        for (int r = 0; r < 4; ++r) {
            int o = obase + 16 * r;
            if (o < out_size) out[o] = 2.0f * acc[r];
        }
    }
}

extern "C" void kernel_launch(void* const* d_in, const int* in_sizes, int n_in,
                              void* d_out, int out_size, void* d_ws, size_t ws_size,
                              hipStream_t stream)
{
    const float* x    = (const float*)d_in[0];
    const float* filt = (const float*)d_in[1];
    float* out        = (float*)d_out;
    const int N       = in_sizes[0];

    const int n_pairs = (out_size + 1) / 2;
    const int blocks  = (n_pairs + GPB - 1) / GPB;
    resample23_mfma<<<blocks, BT, 0, stream>>>(x, filt, out, N, out_size);
}